// Round 8
// baseline (258.222 us; speedup 1.0000x reference)
//
#include <hip/hip_runtime.h>
#include <math.h>

#define CIN   256
#define COUT  256
#define H     64
#define W     64
#define HW    4096
#define KK    9
#define KC    2304
#define NOFF  27
#define B_    4
#define EPS   1e-5f
#define OM3S  (B_ * NOFF * HW)   // floats per offconv partial buffer

typedef __attribute__((ext_vector_type(4))) float f32x4;
typedef __attribute__((ext_vector_type(8))) short s16x8;

static __device__ __forceinline__ unsigned short f2bf(float f) {
  unsigned u = __builtin_bit_cast(unsigned, f);
  u += 0x7FFF + ((u >> 16) & 1);
  return (unsigned short)(u >> 16);
}
static __device__ __forceinline__ float bflo(unsigned u) {
  return __builtin_bit_cast(float, u << 16);
}
static __device__ __forceinline__ float bfhi(unsigned u) {
  return __builtin_bit_cast(float, u & 0xffff0000u);
}
static __device__ __forceinline__ unsigned packbf(float lo, float hi) {
  unsigned ul = __builtin_bit_cast(unsigned, lo);
  unsigned uh = __builtin_bit_cast(unsigned, hi);
  ul += 0x7FFF + ((ul >> 16) & 1);
  uh += 0x7FFF + ((uh >> 16) & 1);
  return (ul >> 16) | (uh & 0xffff0000u);
}

// ---------------------------------------------------------------------------
// prep: fused xprep + weight prep + gstat zero.
//  blocks [0,256):     x NCHW f32 -> xT NHWC bf16
//  blocks [256,544):   wBf  main-weight MFMA-B-fragment order:
//                      packet p=(k2*16+tn)*64+lane, elem j: co=tn*16+(lane&15),
//                      k'=k2*32+(lane>>4)*8+j, k'=kt*256+c
//  blocks [544,580):   wOBf offset-weight fragment order (oc>=27 zero)
//  block 580:          zero gstat
// ---------------------------------------------------------------------------
__global__ __launch_bounds__(256) void prep_kernel(
    const float* __restrict__ x, const float* __restrict__ w,
    const float* __restrict__ w_off, unsigned short* __restrict__ xT,
    unsigned short* __restrict__ wBf, unsigned short* __restrict__ wOBf,
    float* __restrict__ gstat) {
  int bi = blockIdx.x;
  int t = threadIdx.x;
  if (bi < 256) {
    __shared__ unsigned short tile[64][272];
    int b = bi >> 6, y = bi & 63;
    const float* src = x + (size_t)b * CIN * HW + y * W;
    for (int r = 0; r < 64; ++r) {
      int idx = r * 256 + t;
      int c = idx >> 6, ww = idx & 63;
      tile[ww][c] = f2bf(src[(size_t)c * HW + ww]);
    }
    __syncthreads();
    unsigned short* dst = xT + ((size_t)(b * 64 + y) * 64) * 256;
    for (int r = 0; r < 8; ++r) {
      int idx = r * 2048 + t * 8;
      int ww = idx >> 8, c = idx & 255;
      *(uint4*)(dst + idx) = *(const uint4*)&tile[ww][c];
    }
  } else if (bi < 544) {
    int pkt = (bi - 256) * 256 + t;        // [0, 73728)
    int lane = pkt & 63;
    int tn = (pkt >> 6) & 15;
    int k2 = pkt >> 10;
    int co = tn * 16 + (lane & 15);
    int kb = k2 * 32 + (lane >> 4) * 8;
    unsigned short v[8];
#pragma unroll
    for (int j = 0; j < 8; ++j) {
      int kk = kb + j;
      int kt = kk >> 8, c = kk & 255;
      v[j] = f2bf(w[(co * 256 + c) * 9 + kt]);
    }
    *(uint4*)&wBf[(size_t)pkt * 8] = *(const uint4*)v;
  } else if (bi < 580) {
    int pkt = (bi - 544) * 256 + t;        // [0, 9216)
    int lane = pkt & 63;
    int tn = (pkt >> 6) & 1;
    int k2 = pkt >> 7;
    int oc = tn * 16 + (lane & 15);
    int kb = k2 * 32 + (lane >> 4) * 8;
    unsigned short v[8];
#pragma unroll
    for (int j = 0; j < 8; ++j) {
      int kk = kb + j;
      int kt = kk >> 8, c = kk & 255;
      v[j] = (oc < NOFF) ? f2bf(w_off[(oc * 256 + c) * 9 + kt]) : (unsigned short)0;
    }
    *(uint4*)&wOBf[(size_t)pkt * 8] = *(const uint4*)v;
  } else {
    if (t < 128) gstat[t] = 0.f;
  }
}

// ---------------------------------------------------------------------------
// offconv: tap-split x3 partials, no LDS/barriers. grid 768.
// ---------------------------------------------------------------------------
__global__ __launch_bounds__(256) void offconv_mfma_kernel(
    const unsigned short* __restrict__ xT, const unsigned short* __restrict__ wOBf,
    float* __restrict__ om3) {
  int bi = blockIdx.x;
  int ts = bi >> 8;
  int row = bi & 255;
  int b = row >> 6, i = row & 63;
  int t = threadIdx.x, lane = t & 63, wv = t >> 6;
  int lr = lane & 15, lq = lane >> 4;
  int p = wv * 16 + lr;
  const unsigned short* xb = xT + (size_t)b * (HW * 256);
  f32x4 acc[2] = {};

  for (int kc = 0; kc < 3; ++kc) {
    int kt = ts * 3 + kc;
    int ky = kt / 3, kx = kt % 3;
    int yy = i - 1 + ky, xx = p - 1 + kx;
    bool ok = ((unsigned)yy < 64u) && ((unsigned)xx < 64u);
    const unsigned short* ap = xb + ((ok ? yy * 64 + xx : 0) << 8) + lq * 8;
#pragma unroll
    for (int c8 = 0; c8 < 8; ++c8) {
      uint4 av = uint4{0, 0, 0, 0};
      if (ok) av = *(const uint4*)(ap + c8 * 32);
      int k2 = kt * 8 + c8;
      s16x8 a = __builtin_bit_cast(s16x8, av);
      s16x8 b0 = *(const s16x8*)(wOBf + ((((k2 * 2 + 0) << 6) | lane) << 3));
      s16x8 b1 = *(const s16x8*)(wOBf + ((((k2 * 2 + 1) << 6) | lane) << 3));
      acc[0] = __builtin_amdgcn_mfma_f32_16x16x32_bf16(a, b0, acc[0], 0, 0, 0);
      acc[1] = __builtin_amdgcn_mfma_f32_16x16x32_bf16(a, b1, acc[1], 0, 0, 0);
    }
  }
#pragma unroll
  for (int tn = 0; tn < 2; ++tn) {
    int oc = tn * 16 + lr;
    if (oc < NOFF) {
      float* ob = om3 + (size_t)ts * OM3S + ((b * NOFF + oc) << 12) + i * 64 + wv * 16;
#pragma unroll
      for (int r = 0; r < 4; ++r) ob[lq * 4 + r] = acc[tn][r];
    }
  }
}

// ---------------------------------------------------------------------------
// sampler: build im2col A[pix][k'] bf16 (k' = kt*256 + c). grid 512.
// ---------------------------------------------------------------------------
__global__ __launch_bounds__(256, 2) void sampler_kernel(
    const unsigned short* __restrict__ xT, const float* __restrict__ om3,
    const float* __restrict__ b_off, unsigned short* __restrict__ Aout) {
  __shared__ float tapw[32][KK][4];
  __shared__ int   tapc[32][KK][4];
  int bi = blockIdx.x;
  int b = bi >> 7, i = (bi >> 1) & 63, j0 = (bi & 1) * 32;
  int t = threadIdx.x;
  const unsigned short* xb = xT + (size_t)b * (HW * 256);

  for (int idx = t; idx < 32 * KK; idx += 256) {
    int p = idx / KK, k = idx % KK;
    int pix = i * 64 + j0 + p;
    size_t o = (size_t)(b * NOFF) * HW + pix;
    float offy = om3[o + k * HW] + om3[OM3S + o + k * HW] +
                 om3[2 * OM3S + o + k * HW] + b_off[k];
    float offx = om3[o + (9 + k) * HW] + om3[OM3S + o + (9 + k) * HW] +
                 om3[2 * OM3S + o + (9 + k) * HW] + b_off[9 + k];
    float mval = om3[o + (18 + k) * HW] + om3[OM3S + o + (18 + k) * HW] +
                 om3[2 * OM3S + o + (18 + k) * HW] + b_off[18 + k];
    float mask = 1.f / (1.f + __expf(-mval));
    float py = (float)(i - 1 + k / 3) + offy;
    float px = (float)(j0 + p - 1 + k % 3) + offx;
    float y0f = floorf(py), x0f = floorf(px);
    float wy1 = py - y0f, wx1 = px - x0f;
    int y0 = (int)y0f, x0 = (int)x0f;
    bool y0ok = (unsigned)y0 < 64u, y1ok = (unsigned)(y0 + 1) < 64u;
    bool x0ok = (unsigned)x0 < 64u, x1ok = (unsigned)(x0 + 1) < 64u;
    tapw[p][k][0] = (1.f - wy1) * (1.f - wx1) * mask * (float)(y0ok && x0ok);
    tapw[p][k][1] = (1.f - wy1) * wx1 * mask * (float)(y0ok && x1ok);
    tapw[p][k][2] = wy1 * (1.f - wx1) * mask * (float)(y1ok && x0ok);
    tapw[p][k][3] = wy1 * wx1 * mask * (float)(y1ok && x1ok);
    int y0c = min(max(y0, 0), 63), y1c = min(max(y0 + 1, 0), 63);
    int x0c = min(max(x0, 0), 63), x1c = min(max(x0 + 1, 0), 63);
    tapc[p][k][0] = (y0c * 64 + x0c) * 256;
    tapc[p][k][1] = (x1c - x0c) * 256;
    tapc[p][k][2] = (y1c - y0c) * 64 * 256;
    tapc[p][k][3] = 0;
  }
  __syncthreads();

  int p = t >> 3, s = t & 7;
  int gpix = b * 4096 + i * 64 + j0 + p;
  unsigned short* arow = Aout + (size_t)gpix * KC;

  for (int kt = 0; kt < KK; ++kt) {
    f32x4 tw = *(const f32x4*)&tapw[p][kt][0];
    float w00 = tw[0], w01 = tw[1], w10 = tw[2], w11 = tw[3];
    int4 tc = *(const int4*)&tapc[p][kt][0];
    const unsigned short* c00 = xb + tc.x + s * 8;
    int dx = tc.y, dy = tc.z;
#pragma unroll
    for (int g = 0; g < 4; ++g) {
      int c = g * 64 + s * 8;
      int cc = g * 64;
      uint4 v00 = *(const uint4*)(c00 + cc);
      uint4 v01 = *(const uint4*)(c00 + dx + cc);
      uint4 v10 = *(const uint4*)(c00 + dy + cc);
      uint4 v11 = *(const uint4*)(c00 + dy + dx + cc);
      const unsigned* a00 = (const unsigned*)&v00;
      const unsigned* a01 = (const unsigned*)&v01;
      const unsigned* a10 = (const unsigned*)&v10;
      const unsigned* a11 = (const unsigned*)&v11;
      uint4 res;
      unsigned* rr = (unsigned*)&res;
#pragma unroll
      for (int q = 0; q < 4; ++q) {
        float lo = w00 * bflo(a00[q]) + w01 * bflo(a01[q]) +
                   w10 * bflo(a10[q]) + w11 * bflo(a11[q]);
        float hi = w00 * bfhi(a00[q]) + w01 * bfhi(a01[q]) +
                   w10 * bfhi(a10[q]) + w11 * bfhi(a11[q]);
        rr[q] = packbf(lo, hi);
      }
      *(uint4*)(arow + kt * 256 + c) = res;
    }
  }
}

// ---------------------------------------------------------------------------
// gemm: barrier-free, zero-LDS. C[16384][256] = A * W^T.
// Block 64(m) x 128(n), 4 waves, wave tile 32x64. All operands go
// global->register in MFMA fragment order: A rows direct from im2col
// (coalesced 64B lines), B from wBf (contiguous 1KB/wave). 4-deep register
// rotation = prefetch distance 3, ~18 loads in flight per wave, no
// __syncthreads anywhere in the K-loop. grid 512.
// Fused bias + bf16 store + GN partial stats.
// ---------------------------------------------------------------------------
__global__ __launch_bounds__(256, 2) void gemm_kernel(
    const unsigned short* __restrict__ A, const unsigned short* __restrict__ wBf,
    const float* __restrict__ bias, unsigned short* __restrict__ cvt,
    float* __restrict__ gstat) {
  int bi = blockIdx.x;
  int nt0 = (bi & 1) * 8;                  // n-tile base (of 16 tiles)
  int mrow = bi >> 1;                      // b*64 + i
  int m0 = mrow * 64;
  int t = threadIdx.x, lane = t & 63, wv = t >> 6;
  int mh = wv & 1, nh = wv >> 1;
  int lr = lane & 15, lq = lane >> 4;

  const unsigned short* arow0 = A + (size_t)(m0 + mh * 32 + lr) * KC + lq * 8;
  const unsigned short* arow1 = arow0 + 16 * KC;
  // B packet for (k2, tile, lane): wBf[((k2*16 + tile)*64 + lane)*8]
  const unsigned short* bbase = wBf + ((size_t)((nt0 + nh * 4) * 64 + lane)) * 8;

  s16x8 Af[4][2], Bf[4][4];
  f32x4 acc[2][4] = {};

#pragma unroll
  for (int pk = 0; pk < 3; ++pk) {
    Af[pk][0] = *(const s16x8*)(arow0 + pk * 32);
    Af[pk][1] = *(const s16x8*)(arow1 + pk * 32);
#pragma unroll
    for (int tn = 0; tn < 4; ++tn)
      Bf[pk][tn] = *(const s16x8*)(bbase + (size_t)pk * 8192 + tn * 512);
  }

#pragma unroll 4
  for (int k = 0; k < 72; ++k) {
    int cur = k & 3, nx = (k + 3) & 3;
    if (k + 3 < 72) {
      Af[nx][0] = *(const s16x8*)(arow0 + (k + 3) * 32);
      Af[nx][1] = *(const s16x8*)(arow1 + (k + 3) * 32);
#pragma unroll
      for (int tn = 0; tn < 4; ++tn)
        Bf[nx][tn] = *(const s16x8*)(bbase + (size_t)(k + 3) * 8192 + tn * 512);
    }
#pragma unroll
    for (int tm = 0; tm < 2; ++tm)
#pragma unroll
      for (int tn = 0; tn < 4; ++tn)
        acc[tm][tn] = __builtin_amdgcn_mfma_f32_16x16x32_bf16(
            Af[cur][tm], Bf[cur][tn], acc[tm][tn], 0, 0, 0);
  }

  int b = mrow >> 6, ii = mrow & 63;
#pragma unroll
  for (int tn = 0; tn < 4; ++tn) {
    int co = (bi & 1) * 128 + nh * 64 + tn * 16 + lr;
    float bco = bias[co];
    unsigned short* cvb = cvt + (size_t)(b * COUT + co) * HW + ii * 64;
    float s = 0.f, q = 0.f;
#pragma unroll
    for (int tm = 0; tm < 2; ++tm) {
      ushort4 st;
#pragma unroll
      for (int r = 0; r < 4; ++r) {
        float v = acc[tm][tn][r] + bco;
        s += v;
        q += v * v;
        ((unsigned short*)&st)[r] = f2bf(v);
      }
      *(ushort4*)(cvb + mh * 32 + tm * 16 + lq * 4) = st;
    }
#pragma unroll
    for (int off = 32; off > 0; off >>= 1) {
      s += __shfl_down(s, off, 64);
      q += __shfl_down(q, off, 64);
    }
    if (lane == 0) {
      int g = co >> 4;
      atomicAdd(&gstat[(b * 16 + g) * 2 + 0], s);
      atomicAdd(&gstat[(b * 16 + g) * 2 + 1], q);
    }
  }
}

// ---------------------------------------------------------------------------
// gn_apply: normalize bf16 convout -> f32 out. grid 2048.
// ---------------------------------------------------------------------------
__global__ __launch_bounds__(256) void gn_apply_kernel(
    const unsigned short* __restrict__ convout, const float* __restrict__ gstat,
    const float* __restrict__ gamma, const float* __restrict__ beta,
    float* __restrict__ out) {
  int vid = blockIdx.x * 256 + threadIdx.x;
  int e = vid * 8;
  int b = e >> 20;
  int c = (e >> 12) & 255;
  int g = c >> 4;
  float S = gstat[(b * 16 + g) * 2 + 0];
  float Q = gstat[(b * 16 + g) * 2 + 1];
  float mu = S * (1.f / 65536.f);
  float var = Q * (1.f / 65536.f) - mu * mu;
  float rs = rsqrtf(var + EPS);
  float a = rs * gamma[c];
  float bb = beta[c] - mu * a;
  uint4 v = *(const uint4*)(convout + e);
  const unsigned* u = (const unsigned*)&v;
  float4 o0, o1;
  o0.x = bflo(u[0]) * a + bb;  o0.y = bfhi(u[0]) * a + bb;
  o0.z = bflo(u[1]) * a + bb;  o0.w = bfhi(u[1]) * a + bb;
  o1.x = bflo(u[2]) * a + bb;  o1.y = bfhi(u[2]) * a + bb;
  o1.z = bflo(u[3]) * a + bb;  o1.w = bfhi(u[3]) * a + bb;
  *(float4*)(out + e) = o0;
  *(float4*)(out + e + 4) = o1;
}

// ---------------------------------------------------------------------------
extern "C" void kernel_launch(void* const* d_in, const int* in_sizes, int n_in,
                              void* d_out, int out_size, void* d_ws, size_t ws_size,
                              hipStream_t stream) {
  const float* x      = (const float*)d_in[0];
  const float* w_off  = (const float*)d_in[1];
  const float* b_off  = (const float*)d_in[2];
  const float* weight = (const float*)d_in[3];
  const float* bias   = (const float*)d_in[4];
  const float* gamma  = (const float*)d_in[5];
  const float* beta   = (const float*)d_in[6];
  float* out = (float*)d_out;

  // ws layout (~91 MB): om3 | xT(=cvt alias) | wBf | wOBf | A | gstat
  float* om3 = (float*)d_ws;                                  // 5.31 MB
  unsigned short* xT   = (unsigned short*)(om3 + (size_t)3 * OM3S);  // 8.39 MB
  unsigned short* cvt  = xT;                                  // alias: xT dead after sampler
  unsigned short* wBf  = xT + (size_t)B_ * HW * 256;          // 1.18 MB
  unsigned short* wOBf = wBf + (size_t)COUT * KC;             // 147 KB
  unsigned short* Abuf = wOBf + (size_t)32 * KC;              // 75.5 MB
  float* gstat = (float*)(Abuf + (size_t)B_ * HW * KC);       // 512 B

  prep_kernel<<<dim3(581), dim3(256), 0, stream>>>(x, weight, w_off, xT, wBf, wOBf, gstat);
  offconv_mfma_kernel<<<dim3(768), dim3(256), 0, stream>>>(xT, wOBf, om3);
  sampler_kernel<<<dim3(512), dim3(256), 0, stream>>>(xT, om3, b_off, Abuf);
  gemm_kernel<<<dim3(512), dim3(256), 0, stream>>>(Abuf, wBf, bias, cvt, gstat);
  gn_apply_kernel<<<dim3(2048), dim3(256), 0, stream>>>(cvt, gstat, gamma, beta, out);
}

// Round 9
// 206.875 us; speedup vs baseline: 1.2482x; 1.2482x over previous
//
#include <hip/hip_runtime.h>
#include <math.h>

#define CIN   256
#define COUT  256
#define H     64
#define W     64
#define HW    4096
#define KK    9
#define KC    2304
#define NOFF  27
#define B_    4
#define EPS   1e-5f
#define OM3S  (B_ * NOFF * HW)   // floats per offconv partial buffer

typedef __attribute__((ext_vector_type(4))) float f32x4;
typedef __attribute__((ext_vector_type(8))) short s16x8;

static __device__ __forceinline__ unsigned short f2bf(float f) {
  unsigned u = __builtin_bit_cast(unsigned, f);
  u += 0x7FFF + ((u >> 16) & 1);
  return (unsigned short)(u >> 16);
}
static __device__ __forceinline__ float bflo(unsigned u) {
  return __builtin_bit_cast(float, u << 16);
}
static __device__ __forceinline__ float bfhi(unsigned u) {
  return __builtin_bit_cast(float, u & 0xffff0000u);
}
static __device__ __forceinline__ unsigned packbf(float lo, float hi) {
  unsigned ul = __builtin_bit_cast(unsigned, lo);
  unsigned uh = __builtin_bit_cast(unsigned, hi);
  ul += 0x7FFF + ((ul >> 16) & 1);
  uh += 0x7FFF + ((uh >> 16) & 1);
  return (ul >> 16) | (uh & 0xffff0000u);
}
static __device__ __forceinline__ void gl2lds16(const void* g, void* l) {
  __builtin_amdgcn_global_load_lds(
      (const __attribute__((address_space(1))) unsigned int*)g,
      (__attribute__((address_space(3))) unsigned int*)l, 16, 0, 0);
}

// ---------------------------------------------------------------------------
// prep: fused xprep + weight prep + gstat zero.
//  blocks [0,256):        x NCHW f32 -> xT NHWC bf16
//  blocks [256,2560):     wTT[co][kt*256+c] bf16 row-major (GEMM B)
//  blocks [2560,2596):    wOBf offset-weight MFMA fragment order (oc>=27 zero)
//  block 2596:            zero gstat
// ---------------------------------------------------------------------------
__global__ __launch_bounds__(256) void prep_kernel(
    const float* __restrict__ x, const float* __restrict__ w,
    const float* __restrict__ w_off, unsigned short* __restrict__ xT,
    unsigned short* __restrict__ wTT, unsigned short* __restrict__ wOBf,
    float* __restrict__ gstat) {
  int bi = blockIdx.x;
  int t = threadIdx.x;
  if (bi < 256) {
    __shared__ unsigned short tile[64][272];
    int b = bi >> 6, y = bi & 63;
    const float* src = x + (size_t)b * CIN * HW + y * W;
    for (int r = 0; r < 64; ++r) {
      int idx = r * 256 + t;
      int c = idx >> 6, ww = idx & 63;
      tile[ww][c] = f2bf(src[(size_t)c * HW + ww]);
    }
    __syncthreads();
    unsigned short* dst = xT + ((size_t)(b * 64 + y) * 64) * 256;
    for (int r = 0; r < 8; ++r) {
      int idx = r * 2048 + t * 8;
      int ww = idx >> 8, c = idx & 255;
      *(uint4*)(dst + idx) = *(const uint4*)&tile[ww][c];
    }
  } else if (bi < 2560) {
    int idx = (bi - 256) * 256 + t;        // co*2304 + kt*256 + c
    int c  = idx & 255;
    int kt = (idx >> 8) % 9;
    int co = idx / KC;
    wTT[idx] = f2bf(w[(co * 256 + c) * 9 + kt]);
  } else if (bi < 2596) {
    int pkt = (bi - 2560) * 256 + t;       // [0, 9216)
    int lane = pkt & 63;
    int tn = (pkt >> 6) & 1;
    int k2 = pkt >> 7;
    int oc = tn * 16 + (lane & 15);
    int kb = k2 * 32 + (lane >> 4) * 8;
    unsigned short v[8];
#pragma unroll
    for (int j = 0; j < 8; ++j) {
      int kk = kb + j;
      int kt = kk >> 8, c = kk & 255;
      v[j] = (oc < NOFF) ? f2bf(w_off[(oc * 256 + c) * 9 + kt]) : (unsigned short)0;
    }
    *(uint4*)&wOBf[(size_t)pkt * 8] = *(const uint4*)v;
  } else {
    if (t < 128) gstat[t] = 0.f;
  }
}

// ---------------------------------------------------------------------------
// offconv: tap-split x3 partials, no LDS/barriers. grid 768.
// ---------------------------------------------------------------------------
__global__ __launch_bounds__(256) void offconv_mfma_kernel(
    const unsigned short* __restrict__ xT, const unsigned short* __restrict__ wOBf,
    float* __restrict__ om3) {
  int bi = blockIdx.x;
  int ts = bi >> 8;
  int row = bi & 255;
  int b = row >> 6, i = row & 63;
  int t = threadIdx.x, lane = t & 63, wv = t >> 6;
  int lr = lane & 15, lq = lane >> 4;
  int p = wv * 16 + lr;
  const unsigned short* xb = xT + (size_t)b * (HW * 256);
  f32x4 acc[2] = {};

  for (int kc = 0; kc < 3; ++kc) {
    int kt = ts * 3 + kc;
    int ky = kt / 3, kx = kt % 3;
    int yy = i - 1 + ky, xx = p - 1 + kx;
    bool ok = ((unsigned)yy < 64u) && ((unsigned)xx < 64u);
    const unsigned short* ap = xb + ((ok ? yy * 64 + xx : 0) << 8) + lq * 8;
#pragma unroll
    for (int c8 = 0; c8 < 8; ++c8) {
      uint4 av = uint4{0, 0, 0, 0};
      if (ok) av = *(const uint4*)(ap + c8 * 32);
      int k2 = kt * 8 + c8;
      s16x8 a = __builtin_bit_cast(s16x8, av);
      s16x8 b0 = *(const s16x8*)(wOBf + ((((k2 * 2 + 0) << 6) | lane) << 3));
      s16x8 b1 = *(const s16x8*)(wOBf + ((((k2 * 2 + 1) << 6) | lane) << 3));
      acc[0] = __builtin_amdgcn_mfma_f32_16x16x32_bf16(a, b0, acc[0], 0, 0, 0);
      acc[1] = __builtin_amdgcn_mfma_f32_16x16x32_bf16(a, b1, acc[1], 0, 0, 0);
    }
  }
#pragma unroll
  for (int tn = 0; tn < 2; ++tn) {
    int oc = tn * 16 + lr;
    if (oc < NOFF) {
      float* ob = om3 + (size_t)ts * OM3S + ((b * NOFF + oc) << 12) + i * 64 + wv * 16;
#pragma unroll
      for (int r = 0; r < 4; ++r) ob[lq * 4 + r] = acc[tn][r];
    }
  }
}

// ---------------------------------------------------------------------------
// sampler: build im2col A[pix][k'] bf16 (k' = kt*256 + c). grid 512.
// ---------------------------------------------------------------------------
__global__ __launch_bounds__(256, 2) void sampler_kernel(
    const unsigned short* __restrict__ xT, const float* __restrict__ om3,
    const float* __restrict__ b_off, unsigned short* __restrict__ Aout) {
  __shared__ float tapw[32][KK][4];
  __shared__ int   tapc[32][KK][4];
  int bi = blockIdx.x;
  int b = bi >> 7, i = (bi >> 1) & 63, j0 = (bi & 1) * 32;
  int t = threadIdx.x;
  const unsigned short* xb = xT + (size_t)b * (HW * 256);

  for (int idx = t; idx < 32 * KK; idx += 256) {
    int p = idx / KK, k = idx % KK;
    int pix = i * 64 + j0 + p;
    size_t o = (size_t)(b * NOFF) * HW + pix;
    float offy = om3[o + k * HW] + om3[OM3S + o + k * HW] +
                 om3[2 * OM3S + o + k * HW] + b_off[k];
    float offx = om3[o + (9 + k) * HW] + om3[OM3S + o + (9 + k) * HW] +
                 om3[2 * OM3S + o + (9 + k) * HW] + b_off[9 + k];
    float mval = om3[o + (18 + k) * HW] + om3[OM3S + o + (18 + k) * HW] +
                 om3[2 * OM3S + o + (18 + k) * HW] + b_off[18 + k];
    float mask = 1.f / (1.f + __expf(-mval));
    float py = (float)(i - 1 + k / 3) + offy;
    float px = (float)(j0 + p - 1 + k % 3) + offx;
    float y0f = floorf(py), x0f = floorf(px);
    float wy1 = py - y0f, wx1 = px - x0f;
    int y0 = (int)y0f, x0 = (int)x0f;
    bool y0ok = (unsigned)y0 < 64u, y1ok = (unsigned)(y0 + 1) < 64u;
    bool x0ok = (unsigned)x0 < 64u, x1ok = (unsigned)(x0 + 1) < 64u;
    tapw[p][k][0] = (1.f - wy1) * (1.f - wx1) * mask * (float)(y0ok && x0ok);
    tapw[p][k][1] = (1.f - wy1) * wx1 * mask * (float)(y0ok && x1ok);
    tapw[p][k][2] = wy1 * (1.f - wx1) * mask * (float)(y1ok && x0ok);
    tapw[p][k][3] = wy1 * wx1 * mask * (float)(y1ok && x1ok);
    int y0c = min(max(y0, 0), 63), y1c = min(max(y0 + 1, 0), 63);
    int x0c = min(max(x0, 0), 63), x1c = min(max(x0 + 1, 0), 63);
    tapc[p][k][0] = (y0c * 64 + x0c) * 256;
    tapc[p][k][1] = (x1c - x0c) * 256;
    tapc[p][k][2] = (y1c - y0c) * 64 * 256;
    tapc[p][k][3] = 0;
  }
  __syncthreads();

  int p = t >> 3, s = t & 7;
  int gpix = b * 4096 + i * 64 + j0 + p;
  unsigned short* arow = Aout + (size_t)gpix * KC;

  for (int kt = 0; kt < KK; ++kt) {
    f32x4 tw = *(const f32x4*)&tapw[p][kt][0];
    float w00 = tw[0], w01 = tw[1], w10 = tw[2], w11 = tw[3];
    int4 tc = *(const int4*)&tapc[p][kt][0];
    const unsigned short* c00 = xb + tc.x + s * 8;
    int dx = tc.y, dy = tc.z;
#pragma unroll
    for (int g = 0; g < 4; ++g) {
      int c = g * 64 + s * 8;
      int cc = g * 64;
      uint4 v00 = *(const uint4*)(c00 + cc);
      uint4 v01 = *(const uint4*)(c00 + dx + cc);
      uint4 v10 = *(const uint4*)(c00 + dy + cc);
      uint4 v11 = *(const uint4*)(c00 + dy + dx + cc);
      const unsigned* a00 = (const unsigned*)&v00;
      const unsigned* a01 = (const unsigned*)&v01;
      const unsigned* a10 = (const unsigned*)&v10;
      const unsigned* a11 = (const unsigned*)&v11;
      uint4 res;
      unsigned* rr = (unsigned*)&res;
#pragma unroll
      for (int q = 0; q < 4; ++q) {
        float lo = w00 * bflo(a00[q]) + w01 * bflo(a01[q]) +
                   w10 * bflo(a10[q]) + w11 * bflo(a11[q]);
        float hi = w00 * bfhi(a00[q]) + w01 * bfhi(a01[q]) +
                   w10 * bfhi(a10[q]) + w11 * bfhi(a11[q]);
        rr[q] = packbf(lo, hi);
      }
      *(uint4*)(arow + kt * 256 + c) = res;
    }
  }
}

// ---------------------------------------------------------------------------
// gemm: C[16384][256] = A[16384][2304] * wTT[256][2304]^T.
// Tile 64(m) x 128(n), BK=64, DOUBLE-BUFFERED LDS (24 KB x 2), ONE barrier
// per iteration: stage(k+1) issued before MFMA(k), so its drain at the next
// barrier is covered by compute. XOR swizzle (chunk = pos^rowq staging,
// (kh*4+lq)^(r&7) reads) keeps bank conflicts at 0. 4 waves, wave 32x64.
// grid 512. Fused bias + bf16 store + GN partial stats.
// ---------------------------------------------------------------------------
__global__ __launch_bounds__(256, 2) void gemm_kernel(
    const unsigned short* __restrict__ A, const unsigned short* __restrict__ wTT,
    const float* __restrict__ bias, unsigned short* __restrict__ cvt,
    float* __restrict__ gstat) {
  // per buffer: A rows [0,64) pitch 128B (8 KB), B rows [64,192) (16 KB)
  __shared__ unsigned short lds[2][192 * 64];
  int bi = blockIdx.x;
  int n0 = (bi & 1) * 128;
  int mrow = bi >> 1;                        // b*64 + i
  int m0 = mrow * 64;
  int t = threadIdx.x, lane = t & 63, wv = t >> 6;
  int mh = wv & 1, nh = wv >> 1;
  int lr = lane & 15, lq = lane >> 4;
  int rowq = lane >> 3, pos = lane & 7;      // staging roles (8 rows/inst)
  int swz = pos ^ rowq;                      // base rows are %8==0

  // per-lane global sources (row part fixed, k advances)
  const char* Asrc0 = (const char*)A + (size_t)(m0 + wv * 16 + rowq) * 4608 + swz * 16;
  const char* Asrc1 = Asrc0 + 8 * 4608;
  const char* Bsrc[4];
#pragma unroll
  for (int q = 0; q < 4; ++q)
    Bsrc[q] = (const char*)wTT + (size_t)(n0 + wv * 32 + q * 8 + rowq) * 4608 + swz * 16;

  f32x4 acc[2][4] = {};

  // prologue: stage chunk 0 into buf 0
  {
    char* buf = (char*)lds[0];
    gl2lds16(Asrc0, buf + (wv * 16) * 128);
    gl2lds16(Asrc1, buf + (wv * 16 + 8) * 128);
#pragma unroll
    for (int q = 0; q < 4; ++q)
      gl2lds16(Bsrc[q], buf + (64 + wv * 32 + q * 8) * 128);
  }

  for (int k = 0; k < 36; ++k) {
    int cur = k & 1;
    __syncthreads();   // staging(k) complete; buf nxt consumers (k-1) done
    if (k + 1 < 36) {
      char* buf = (char*)lds[cur ^ 1];
      int koff = (k + 1) * 128;
      gl2lds16(Asrc0 + koff, buf + (wv * 16) * 128);
      gl2lds16(Asrc1 + koff, buf + (wv * 16 + 8) * 128);
#pragma unroll
      for (int q = 0; q < 4; ++q)
        gl2lds16(Bsrc[q] + koff, buf + (64 + wv * 32 + q * 8) * 128);
    }
    const char* buf = (const char*)lds[cur];
#pragma unroll
    for (int kh = 0; kh < 2; ++kh) {
      s16x8 af[2], bf[4];
#pragma unroll
      for (int tm = 0; tm < 2; ++tm) {
        int r = mh * 32 + tm * 16 + lr;
        af[tm] = *(const s16x8*)(buf + r * 128 + (((kh * 4 + lq) ^ (r & 7)) * 16));
      }
#pragma unroll
      for (int tn = 0; tn < 4; ++tn) {
        int r = nh * 64 + tn * 16 + lr;
        bf[tn] = *(const s16x8*)(buf + (64 + r) * 128 + (((kh * 4 + lq) ^ (r & 7)) * 16));
      }
#pragma unroll
      for (int tm = 0; tm < 2; ++tm)
#pragma unroll
        for (int tn = 0; tn < 4; ++tn)
          acc[tm][tn] = __builtin_amdgcn_mfma_f32_16x16x32_bf16(
              af[tm], bf[tn], acc[tm][tn], 0, 0, 0);
    }
  }

  int b = mrow >> 6, ii = mrow & 63;
#pragma unroll
  for (int tn = 0; tn < 4; ++tn) {
    int co = n0 + nh * 64 + tn * 16 + lr;
    float bco = bias[co];
    unsigned short* cvb = cvt + (size_t)(b * COUT + co) * HW + ii * 64;
    float s = 0.f, q = 0.f;
#pragma unroll
    for (int tm = 0; tm < 2; ++tm) {
      ushort4 st;
#pragma unroll
      for (int r = 0; r < 4; ++r) {
        float v = acc[tm][tn][r] + bco;
        s += v;
        q += v * v;
        ((unsigned short*)&st)[r] = f2bf(v);
      }
      *(ushort4*)(cvb + mh * 32 + tm * 16 + lq * 4) = st;
    }
#pragma unroll
    for (int off = 32; off > 0; off >>= 1) {
      s += __shfl_down(s, off, 64);
      q += __shfl_down(q, off, 64);
    }
    if (lane == 0) {
      int g = co >> 4;
      atomicAdd(&gstat[(b * 16 + g) * 2 + 0], s);
      atomicAdd(&gstat[(b * 16 + g) * 2 + 1], q);
    }
  }
}

// ---------------------------------------------------------------------------
// gn_apply: normalize bf16 convout -> f32 out. grid 2048.
// ---------------------------------------------------------------------------
__global__ __launch_bounds__(256) void gn_apply_kernel(
    const unsigned short* __restrict__ convout, const float* __restrict__ gstat,
    const float* __restrict__ gamma, const float* __restrict__ beta,
    float* __restrict__ out) {
  int vid = blockIdx.x * 256 + threadIdx.x;
  int e = vid * 8;
  int b = e >> 20;
  int c = (e >> 12) & 255;
  int g = c >> 4;
  float S = gstat[(b * 16 + g) * 2 + 0];
  float Q = gstat[(b * 16 + g) * 2 + 1];
  float mu = S * (1.f / 65536.f);
  float var = Q * (1.f / 65536.f) - mu * mu;
  float rs = rsqrtf(var + EPS);
  float a = rs * gamma[c];
  float bb = beta[c] - mu * a;
  uint4 v = *(const uint4*)(convout + e);
  const unsigned* u = (const unsigned*)&v;
  float4 o0, o1;
  o0.x = bflo(u[0]) * a + bb;  o0.y = bfhi(u[0]) * a + bb;
  o0.z = bflo(u[1]) * a + bb;  o0.w = bfhi(u[1]) * a + bb;
  o1.x = bflo(u[2]) * a + bb;  o1.y = bfhi(u[2]) * a + bb;
  o1.z = bflo(u[3]) * a + bb;  o1.w = bfhi(u[3]) * a + bb;
  *(float4*)(out + e) = o0;
  *(float4*)(out + e + 4) = o1;
}

// ---------------------------------------------------------------------------
extern "C" void kernel_launch(void* const* d_in, const int* in_sizes, int n_in,
                              void* d_out, int out_size, void* d_ws, size_t ws_size,
                              hipStream_t stream) {
  const float* x      = (const float*)d_in[0];
  const float* w_off  = (const float*)d_in[1];
  const float* b_off  = (const float*)d_in[2];
  const float* weight = (const float*)d_in[3];
  const float* bias   = (const float*)d_in[4];
  const float* gamma  = (const float*)d_in[5];
  const float* beta   = (const float*)d_in[6];
  float* out = (float*)d_out;

  // ws layout (~91 MB): om3 | xT(=cvt alias) | wTT | wOBf | A | gstat
  float* om3 = (float*)d_ws;                                  // 5.31 MB
  unsigned short* xT   = (unsigned short*)(om3 + (size_t)3 * OM3S);  // 8.39 MB
  unsigned short* cvt  = xT;                                  // alias: xT dead after sampler
  unsigned short* wTT  = xT + (size_t)B_ * HW * 256;          // 1.18 MB
  unsigned short* wOBf = wTT + (size_t)COUT * KC;             // 147 KB
  unsigned short* Abuf = wOBf + (size_t)32 * KC;              // 75.5 MB
  float* gstat = (float*)(Abuf + (size_t)B_ * HW * KC);       // 512 B

  prep_kernel<<<dim3(2597), dim3(256), 0, stream>>>(x, weight, w_off, xT, wTT, wOBf, gstat);
  offconv_mfma_kernel<<<dim3(768), dim3(256), 0, stream>>>(xT, wOBf, om3);
  sampler_kernel<<<dim3(512), dim3(256), 0, stream>>>(xT, om3, b_off, Abuf);
  gemm_kernel<<<dim3(512), dim3(256), 0, stream>>>(Abuf, wTT, bias, cvt, gstat);
  gn_apply_kernel<<<dim3(2048), dim3(256), 0, stream>>>(cvt, gstat, gamma, beta, out);
}